// Round 1
// baseline (361.111 us; speedup 1.0000x reference)
//
#include <hip/hip_runtime.h>
#include <stdint.h>

// B=16, C=256, L=16384, K=S=4 -> OL=4096. fp32 in/out.
// Persistent-ish decomposition: 512 blocks (2/CU, fully resident), each owns
// 4 consecutive otiles of one b. Tile payload (256 ch x 128 l) lives in
// registers (v[16] f4/thread). Next tile's loads are issued during the
// current tile's mk loop; raw s_barrier + lgkmcnt(0)-only keeps those loads
// in flight across B3/B4 (no vmcnt(0) drain, unlike __syncthreads()).
#define B_      16
#define C_      256
#define L_      16384
#define OL_     4096
#define OT      32          // outputs per tile
#define TL      128         // input l per tile (OT*4)
#define NTHR    512
#define TPB     4           // tiles per block, consecutive otiles, same b
#define NBLK    ((B_ * (OL_ / OT)) / TPB)   // 512

typedef float f4 __attribute__((ext_vector_type(4)));

// LDS-producer-ordered barrier WITHOUT the vmcnt(0) drain __syncthreads()
// would emit: global prefetch loads stay outstanding across it.
#define BARRIER_LGKM() do {                                   \
    asm volatile("s_waitcnt lgkmcnt(0)" ::: "memory");        \
    __builtin_amdgcn_s_barrier();                             \
    asm volatile("" ::: "memory");                            \
} while (0)

__global__ __launch_bounds__(NTHR, 4)
void havgpool_hyp_kernel(const float* __restrict__ x, float* __restrict__ out) {
    __shared__ float sP[8][TL];    // per-wave sum_c(x^2) partials
    __shared__ float sA1[TL];      // per-l combine coefficient
    __shared__ float sQ[8][OT];    // per-wave mK2 partials
    __shared__ float sInvm[OT];    // per-output final scale

    const int t     = threadIdx.x;
    const int blk   = blockIdx.x;       // 0..511
    const int tile0 = blk * TPB;        // first global tile (b*128 + otile)
    const int b     = tile0 >> 7;       // constant across the 4 tiles
    const int ot0   = tile0 & 127;
    const int j     = t & 31;           // output / l-quad index within tile
    const int rbase = t >> 5;           // channel-group 0..15
    const int lane  = t & 63;
    const int w     = t >> 6;           // wave 0..7

    const float* src = x   + ((size_t)b * C_ * L_  + (size_t)ot0 * TL + 4 * j);
    float*       op  = out + ((size_t)b * C_ * OL_ + (size_t)ot0 * OT + j);

    f4 v[16];
    // Prologue: issue tile-0 loads (2 rows x 512B contiguous per wave-instr).
    #pragma unroll
    for (int it = 0; it < 16; ++it)
        v[it] = __builtin_nontemporal_load((const f4*)(src + (size_t)(it * 16 + rbase) * L_));

    #pragma unroll
    for (int i = 0; i < TPB; ++i) {
        const float* nsrc = src + (size_t)(i + 1) * TL;   // next tile, +512B/row

        // ---- sum_c x^2 per l (consumes v as loads land; staggered vmcnt waits)
        float a0 = 0.f, a1 = 0.f, a2 = 0.f, a3 = 0.f;
        #pragma unroll
        for (int it = 0; it < 16; ++it) {
            a0 += v[it].x * v[it].x;
            a1 += v[it].y * v[it].y;
            a2 += v[it].z * v[it].z;
            a3 += v[it].w * v[it].w;
        }
        a0 += __shfl_xor(a0, 32, 64);
        a1 += __shfl_xor(a1, 32, 64);
        a2 += __shfl_xor(a2, 32, 64);
        a3 += __shfl_xor(a3, 32, 64);
        if (lane < 32) {
            sP[w][4 * j + 0] = a0;
            sP[w][4 * j + 1] = a1;
            sP[w][4 * j + 2] = a2;
            sP[w][4 * j + 3] = a3;
        }
        BARRIER_LGKM();                                   // B1

        // ---- per-l scalars: x2 -> gamma -> a1[l] = 2*g*inv1/G
        if (t < TL) {
            float x2 = 0.f;
            #pragma unroll
            for (int k = 0; k < 8; ++k) x2 += sP[k][t];   // stride-1, conflict-free
            const float inv1 = 1.0f / (1.0f + x2);
            const float xk2  = 4.0f * x2 * inv1 * inv1;
            const float g    = rsqrtf(fmaxf(1.0f - xk2, 1e-7f));
            float G = g;
            G += __shfl_xor(G, 1, 64);
            G += __shfl_xor(G, 2, 64);
            sA1[t] = 2.0f * g * inv1 / G;
        }
        BARRIER_LGKM();                                   // B2

        // ---- mK per (channel, output); prefetch next tile into dying v[]
        const float c0 = sA1[4 * j + 0];
        const float c1 = sA1[4 * j + 1];
        const float c2 = sA1[4 * j + 2];
        const float c3 = sA1[4 * j + 3];
        float mk[16];
        float q = 0.f;
        #pragma unroll
        for (int it = 0; it < 16; ++it) {
            const f4 vv = v[it];
            const float m = vv.x * c0 + vv.y * c1 + vv.z * c2 + vv.w * c3;
            mk[it] = m;
            q += m * m;
            if (i < TPB - 1)   // issue next tile's load; stays in flight past B3/B4
                v[it] = __builtin_nontemporal_load((const f4*)(nsrc + (size_t)(it * 16 + rbase) * L_));
        }
        q += __shfl_xor(q, 32, 64);
        if (lane < 32) sQ[w][j] = q;
        BARRIER_LGKM();                                   // B3

        if (t < OT) {
            float m2 = 0.f;
            #pragma unroll
            for (int k = 0; k < 8; ++k) m2 += sQ[k][t];
            sInvm[t] = 1.0f / (1.0f + sqrtf(fmaxf(1.0f - m2, 1e-7f)));
        }
        BARRIER_LGKM();                                   // B4

        // ---- scale + store (independent of in-flight prefetch loads)
        const float s = sInvm[j];
        #pragma unroll
        for (int it = 0; it < 16; ++it)
            __builtin_nontemporal_store(mk[it] * s,
                op + (size_t)(it * 16 + rbase) * OL_ + (size_t)i * OT);
    }
}

extern "C" void kernel_launch(void* const* d_in, const int* in_sizes, int n_in,
                              void* d_out, int out_size, void* d_ws, size_t ws_size,
                              hipStream_t stream) {
    const float* x = (const float*)d_in[0];
    float* out = (float*)d_out;
    havgpool_hyp_kernel<<<dim3(NBLK), NTHR, 0, stream>>>(x, out);
}